// Round 1
// 765.386 us; speedup vs baseline: 1.0739x; 1.0739x over previous
//
#include <hip/hip_runtime.h>

// TriPlaneField: 4-scale triplane bilinear sampling with cumulative-sum concat.
// Strategy: (1) ONE fused transpose kernel: [3,C,r,r] -> [3,r,r,C] for all four
// scales. Each 256-thread block handles 128 consecutive pixels x all 72 channels:
// input = 72 contiguous 512B rows (coalesced float4 reads), output = one
// contiguous 36KB block (perfectly coalesced float4 stream). LDS staged with
// stride-129 padding. (2) gather kernel unchanged: one thread per
// (point, plane, 4-channel group) using float4 loads from channel-last grids.

#define TP_C 72
#define TP_PLANES 3
#define TP_SCALES 4
#define TP_INV_BOUNDS 0.625f  // 1/1.6
#define TP_CVEC (TP_C / 4)    // 18 float4 groups per (n,p)

// Tile counts per scale: 3*r*r/128  -> 96, 384, 1536, 6144 ; cumulative below.
#define TP_TILES0 96
#define TP_TILES1 480
#define TP_TILES2 2016
#define TP_TILES3 8160

// ---------------- fused transpose: [3, C, r, r] -> [3, r, r, C] ----------------
// One block = 128 consecutive pixels (linear y*r+x) x 72 channels of one plane.
// r*r is a multiple of 128 for all scales, so a tile never crosses a plane.
__global__ __launch_bounds__(256) void transpose_all_kernel(
    const float* __restrict__ g0, const float* __restrict__ g1,
    const float* __restrict__ g2, const float* __restrict__ g3,
    float* __restrict__ t0, float* __restrict__ t1,
    float* __restrict__ t2, float* __restrict__ t3)
{
    int b = blockIdx.x;
    const float* in;
    float* out;
    int rr, tile;
    if (b < TP_TILES0)      { in = g0; out = t0; rr = 64 * 64;   tile = b; }
    else if (b < TP_TILES1) { in = g1; out = t1; rr = 128 * 128; tile = b - TP_TILES0; }
    else if (b < TP_TILES2) { in = g2; out = t2; rr = 256 * 256; tile = b - TP_TILES1; }
    else                    { in = g3; out = t3; rr = 512 * 512; tile = b - TP_TILES2; }

    int P0  = tile * 128;       // global pixel index within [0, 3*rr)
    int p   = P0 / rr;          // plane
    int px0 = P0 - p * rr;      // pixel within plane

    // LDS tile: [72 channels][128 pixels], row stride 129 floats (pad 1)
    __shared__ float lds[TP_C * 129];

    const float* inp = in + ((size_t)p * TP_C) * (size_t)rr + px0;
    int t = threadIdx.x;

    // Load phase: 72 rows x 32 float4 = 2304 float4, 9 per thread.
    // Consecutive lanes -> consecutive float4 within a 512B channel row.
    #pragma unroll
    for (int j = 0; j < 9; ++j) {
        int idx = j * 256 + t;
        int c   = idx >> 5;           // channel row (0..71)
        int q4  = idx & 31;           // float4 index within row (0..31)
        float4 v = *(const float4*)(inp + (size_t)c * rr + q4 * 4);
        float* l = lds + c * 129 + q4 * 4;
        l[0] = v.x; l[1] = v.y; l[2] = v.z; l[3] = v.w;
    }
    __syncthreads();

    // Store phase: output tile is one contiguous 128*72*4B = 36864B block.
    // idx = q*18 + c4  ->  float offset idx*4 = q*72 + c4*4.
    float* outp = out + (size_t)P0 * TP_C;
    #pragma unroll
    for (int j = 0; j < 9; ++j) {
        int idx = j * 256 + t;
        int q   = idx / 18;           // pixel within tile
        int c4  = idx - q * 18;       // channel float4 group
        const float* l = lds + (c4 * 4) * 129 + q;
        float4 v;
        v.x = l[0 * 129];
        v.y = l[1 * 129];
        v.z = l[2 * 129];
        v.w = l[3 * 129];
        *(float4*)(outp + (size_t)idx * 4) = v;
    }
}

// ---------------- gather: bilinear sample from channel-last grids ----------------
__global__ __launch_bounds__(256) void triplane_gather_kernel(
    const float* __restrict__ pts,
    const float* __restrict__ t0,
    const float* __restrict__ t1,
    const float* __restrict__ t2,
    const float* __restrict__ t3,
    float* __restrict__ out,
    int N)
{
    int idx = blockIdx.x * blockDim.x + threadIdx.x;
    int total = N * TP_PLANES * TP_CVEC;
    if (idx >= total) return;

    int cv = idx % TP_CVEC;           // which float4 group of channels
    int t  = idx / TP_CVEC;
    int p  = t % TP_PLANES;
    int n  = t / TP_PLANES;

    float nx = -pts[n * 3 + 0] * TP_INV_BOUNDS;
    float ny = -pts[n * 3 + 1] * TP_INV_BOUNDS;
    float nz = -pts[n * 3 + 2] * TP_INV_BOUNDS;

    float cx, cy;
    if (p == 0)      { cx = nx; cy = ny; }
    else if (p == 1) { cx = nx; cy = nz; }
    else             { cx = ny; cy = nz; }

    const float* grids[TP_SCALES] = { t0, t1, t2, t3 };
    const int    res[TP_SCALES]   = { 64, 128, 256, 512 };

    float4 acc = make_float4(0.f, 0.f, 0.f, 0.f);
    float* outrow = out + (size_t)n * (TP_SCALES * TP_PLANES * TP_C)
                        + (size_t)p * TP_C + cv * 4;

    #pragma unroll
    for (int s = 0; s < TP_SCALES; ++s) {
        const int r = res[s];
        const float rm1 = (float)(r - 1);

        float fx = (cx + 1.0f) * 0.5f * rm1;
        float fy = (cy + 1.0f) * 0.5f * rm1;
        fx = fminf(fmaxf(fx, 0.0f), rm1);
        fy = fminf(fmaxf(fy, 0.0f), rm1);

        float x0f = floorf(fx);
        float y0f = floorf(fy);
        float wx = fx - x0f;
        float wy = fy - y0f;
        int x0 = (int)x0f;
        int y0 = (int)y0f;
        int x1 = min(x0 + 1, r - 1);
        int y1 = min(y0 + 1, r - 1);

        // channel-last: ((p*r + y)*r + x)*C + c
        const float* g = grids[s] + ((size_t)p * r * r) * TP_C + (size_t)cv * 4;
        const float4* r0c0 = (const float4*)(g + ((size_t)y0 * r + x0) * TP_C);
        const float4* r0c1 = (const float4*)(g + ((size_t)y0 * r + x1) * TP_C);
        const float4* r1c0 = (const float4*)(g + ((size_t)y1 * r + x0) * TP_C);
        const float4* r1c1 = (const float4*)(g + ((size_t)y1 * r + x1) * TP_C);

        float4 v00 = *r0c0;
        float4 v01 = *r0c1;
        float4 v10 = *r1c0;
        float4 v11 = *r1c1;

        float iwx = 1.0f - wx;
        float iwy = 1.0f - wy;

        float tpx, tpy, tpz, tpw, bt;
        tpx = v00.x * iwx + v01.x * wx;
        bt  = v10.x * iwx + v11.x * wx;
        acc.x += tpx * iwy + bt * wy;
        tpy = v00.y * iwx + v01.y * wx;
        bt  = v10.y * iwx + v11.y * wx;
        acc.y += tpy * iwy + bt * wy;
        tpz = v00.z * iwx + v01.z * wx;
        bt  = v10.z * iwx + v11.z * wx;
        acc.z += tpz * iwy + bt * wy;
        tpw = v00.w * iwx + v01.w * wx;
        bt  = v10.w * iwx + v11.w * wx;
        acc.w += tpw * iwy + bt * wy;

        *(float4*)(outrow + s * (TP_PLANES * TP_C)) = acc;
    }
}

extern "C" void kernel_launch(void* const* d_in, const int* in_sizes, int n_in,
                              void* d_out, int out_size, void* d_ws, size_t ws_size,
                              hipStream_t stream) {
    const float* pts = (const float*)d_in[0];
    const float* g[TP_SCALES] = {
        (const float*)d_in[1], (const float*)d_in[2],
        (const float*)d_in[3], (const float*)d_in[4] };
    float* out = (float*)d_out;

    const int res[TP_SCALES] = { 64, 128, 256, 512 };

    // ws layout: transposed grids, scale-major
    float* tg[TP_SCALES];
    size_t off = 0;
    for (int s = 0; s < TP_SCALES; ++s) {
        tg[s] = (float*)d_ws + off;
        off += (size_t)TP_PLANES * TP_C * res[s] * res[s];
    }

    transpose_all_kernel<<<TP_TILES3, 256, 0, stream>>>(
        g[0], g[1], g[2], g[3], tg[0], tg[1], tg[2], tg[3]);

    int N = in_sizes[0] / 3;
    int total = N * TP_PLANES * TP_CVEC;
    int block = 256;
    int grid = (total + block - 1) / block;
    triplane_gather_kernel<<<grid, block, 0, stream>>>(
        pts, tg[0], tg[1], tg[2], tg[3], out, N);
}

// Round 3
// 726.291 us; speedup vs baseline: 1.1317x; 1.0538x over previous
//
#include <hip/hip_runtime.h>

// TriPlaneField: 4-scale triplane bilinear sampling with cumulative-sum concat.
// Pipeline:
//   (1) transpose_all_kernel: [3,C,r,r] -> [3,r,r,C] for all 4 scales in one
//       launch (coalesced both sides, LDS staged). Non-temporal input loads
//       (single-use data, keep caches clean).
//   (2) Morton sort of points (5 bits/dim, 32768 bins): keys+histogram ->
//       prefix scan -> scatter permutation. Gives spatial locality so the
//       big-scale texel reads hit L2/L3 instead of all going to HBM
//       (round-1 FETCH == exact compulsory traffic => zero reuse today).
//   (3) gather kernel processes points in Morton order via perm[], writes
//       output with non-temporal stores (the 345 MB output stream must not
//       evict grid texels from L2/L3).
// NOTE: __builtin_nontemporal_* requires clang native vectors, not
// HIP_vector_type -> use ext_vector_type(4) floats for those accesses.

#define TP_C 72
#define TP_PLANES 3
#define TP_SCALES 4
#define TP_INV_BOUNDS 0.625f  // 1/1.6
#define TP_CVEC (TP_C / 4)    // 18 float4 groups per (n,p)

typedef float tp_f4 __attribute__((ext_vector_type(4)));

// Transpose tile counts per scale: 3*r*r/128 -> 96, 384, 1536, 6144 (cumulative)
#define TP_TILES0 96
#define TP_TILES1 480
#define TP_TILES2 2016
#define TP_TILES3 8160

#define TP_NBINS 32768  // 5 bits per dim, 3D Morton

// ---------------- fused transpose: [3, C, r, r] -> [3, r, r, C] ----------------
__global__ __launch_bounds__(256) void transpose_all_kernel(
    const float* __restrict__ g0, const float* __restrict__ g1,
    const float* __restrict__ g2, const float* __restrict__ g3,
    float* __restrict__ t0, float* __restrict__ t1,
    float* __restrict__ t2, float* __restrict__ t3)
{
    int b = blockIdx.x;
    const float* in;
    float* out;
    int rr, tile;
    if (b < TP_TILES0)      { in = g0; out = t0; rr = 64 * 64;   tile = b; }
    else if (b < TP_TILES1) { in = g1; out = t1; rr = 128 * 128; tile = b - TP_TILES0; }
    else if (b < TP_TILES2) { in = g2; out = t2; rr = 256 * 256; tile = b - TP_TILES1; }
    else                    { in = g3; out = t3; rr = 512 * 512; tile = b - TP_TILES2; }

    int P0  = tile * 128;       // global pixel index within [0, 3*rr)
    int p   = P0 / rr;          // plane
    int px0 = P0 - p * rr;      // pixel within plane

    // LDS tile: [72 channels][128 pixels], row stride 129 floats (pad 1)
    __shared__ float lds[TP_C * 129];

    const float* inp = in + ((size_t)p * TP_C) * (size_t)rr + px0;
    int t = threadIdx.x;

    // Load: 72 rows x 32 float4, coalesced within each 512B channel row.
    #pragma unroll
    for (int j = 0; j < 9; ++j) {
        int idx = j * 256 + t;
        int c   = idx >> 5;           // channel row (0..71)
        int q4  = idx & 31;           // float4 index within row (0..31)
        tp_f4 v = __builtin_nontemporal_load(
            (const tp_f4*)(inp + (size_t)c * rr + q4 * 4));
        float* l = lds + c * 129 + q4 * 4;
        l[0] = v.x; l[1] = v.y; l[2] = v.z; l[3] = v.w;
    }
    __syncthreads();

    // Store: one contiguous 36864B block per tile (keep cached - gather reads it).
    float* outp = out + (size_t)P0 * TP_C;
    #pragma unroll
    for (int j = 0; j < 9; ++j) {
        int idx = j * 256 + t;
        int q   = idx / 18;           // pixel within tile
        int c4  = idx - q * 18;       // channel float4 group
        const float* l = lds + (c4 * 4) * 129 + q;
        float4 v;
        v.x = l[0 * 129];
        v.y = l[1 * 129];
        v.z = l[2 * 129];
        v.w = l[3 * 129];
        *(float4*)(outp + (size_t)idx * 4) = v;
    }
}

// ---------------- Morton sort ----------------
__device__ __forceinline__ unsigned tp_expand5(unsigned v) {
    // 5 bits -> every 3rd bit
    unsigned r = (v & 1);
    r |= (v & 2)  << 2;
    r |= (v & 4)  << 4;
    r |= (v & 8)  << 6;
    r |= (v & 16) << 8;
    return r;
}

__global__ __launch_bounds__(256) void keys_kernel(
    const float* __restrict__ pts, unsigned* __restrict__ keys,
    unsigned* __restrict__ hist, int N)
{
    int n = blockIdx.x * 256 + threadIdx.x;
    if (n >= N) return;
    float nx = fminf(fmaxf(-pts[n * 3 + 0] * TP_INV_BOUNDS, -1.f), 1.f);
    float ny = fminf(fmaxf(-pts[n * 3 + 1] * TP_INV_BOUNDS, -1.f), 1.f);
    float nz = fminf(fmaxf(-pts[n * 3 + 2] * TP_INV_BOUNDS, -1.f), 1.f);
    int qx = min(31, max(0, (int)((nx + 1.f) * 16.f)));
    int qy = min(31, max(0, (int)((ny + 1.f) * 16.f)));
    int qz = min(31, max(0, (int)((nz + 1.f) * 16.f)));
    unsigned key = tp_expand5((unsigned)qx)
                 | (tp_expand5((unsigned)qy) << 1)
                 | (tp_expand5((unsigned)qz) << 2);
    keys[n] = key;
    atomicAdd(&hist[key], 1u);
}

__global__ __launch_bounds__(1024) void prefix_kernel(
    const unsigned* __restrict__ hist, unsigned* __restrict__ binoff)
{
    __shared__ unsigned part[1024];
    int t = threadIdx.x;
    unsigned local[32];
    unsigned s = 0;
    #pragma unroll
    for (int i = 0; i < 32; ++i) { local[i] = hist[t * 32 + i]; s += local[i]; }
    part[t] = s;
    __syncthreads();
    // Hillis-Steele inclusive scan over 1024 partials
    for (int off = 1; off < 1024; off <<= 1) {
        unsigned v = (t >= off) ? part[t - off] : 0u;
        __syncthreads();
        part[t] += v;
        __syncthreads();
    }
    unsigned run = (t == 0) ? 0u : part[t - 1];
    #pragma unroll
    for (int i = 0; i < 32; ++i) { binoff[t * 32 + i] = run; run += local[i]; }
}

__global__ __launch_bounds__(256) void scatter_kernel(
    const unsigned* __restrict__ keys, unsigned* __restrict__ binoff,
    unsigned* __restrict__ perm, int N)
{
    int n = blockIdx.x * 256 + threadIdx.x;
    if (n >= N) return;
    unsigned pos = atomicAdd(&binoff[keys[n]], 1u);
    perm[pos] = n;
}

// ---------------- gather: bilinear sample from channel-last grids ----------------
__global__ __launch_bounds__(256) void triplane_gather_kernel(
    const float* __restrict__ pts,
    const unsigned* __restrict__ perm,
    const float* __restrict__ t0,
    const float* __restrict__ t1,
    const float* __restrict__ t2,
    const float* __restrict__ t3,
    float* __restrict__ out,
    int N)
{
    int idx = blockIdx.x * blockDim.x + threadIdx.x;
    int total = N * TP_PLANES * TP_CVEC;
    if (idx >= total) return;

    int cv = idx % TP_CVEC;           // which float4 group of channels
    int t  = idx / TP_CVEC;
    int p  = t % TP_PLANES;
    int ns = t / TP_PLANES;           // sorted point index
    int n  = (int)perm[ns];           // original point index

    float nx = -pts[n * 3 + 0] * TP_INV_BOUNDS;
    float ny = -pts[n * 3 + 1] * TP_INV_BOUNDS;
    float nz = -pts[n * 3 + 2] * TP_INV_BOUNDS;

    float cx, cy;
    if (p == 0)      { cx = nx; cy = ny; }
    else if (p == 1) { cx = nx; cy = nz; }
    else             { cx = ny; cy = nz; }

    const float* grids[TP_SCALES] = { t0, t1, t2, t3 };
    const int    res[TP_SCALES]   = { 64, 128, 256, 512 };

    float4 acc = make_float4(0.f, 0.f, 0.f, 0.f);
    float* outrow = out + (size_t)n * (TP_SCALES * TP_PLANES * TP_C)
                        + (size_t)p * TP_C + cv * 4;

    #pragma unroll
    for (int s = 0; s < TP_SCALES; ++s) {
        const int r = res[s];
        const float rm1 = (float)(r - 1);

        float fx = (cx + 1.0f) * 0.5f * rm1;
        float fy = (cy + 1.0f) * 0.5f * rm1;
        fx = fminf(fmaxf(fx, 0.0f), rm1);
        fy = fminf(fmaxf(fy, 0.0f), rm1);

        float x0f = floorf(fx);
        float y0f = floorf(fy);
        float wx = fx - x0f;
        float wy = fy - y0f;
        int x0 = (int)x0f;
        int y0 = (int)y0f;
        int x1 = min(x0 + 1, r - 1);
        int y1 = min(y0 + 1, r - 1);

        // channel-last: ((p*r + y)*r + x)*C + c
        const float* g = grids[s] + ((size_t)p * r * r) * TP_C + (size_t)cv * 4;
        float4 v00 = *(const float4*)(g + ((size_t)y0 * r + x0) * TP_C);
        float4 v01 = *(const float4*)(g + ((size_t)y0 * r + x1) * TP_C);
        float4 v10 = *(const float4*)(g + ((size_t)y1 * r + x0) * TP_C);
        float4 v11 = *(const float4*)(g + ((size_t)y1 * r + x1) * TP_C);

        float iwx = 1.0f - wx;
        float iwy = 1.0f - wy;

        float tp0, bt;
        tp0 = v00.x * iwx + v01.x * wx;
        bt  = v10.x * iwx + v11.x * wx;
        acc.x += tp0 * iwy + bt * wy;
        tp0 = v00.y * iwx + v01.y * wx;
        bt  = v10.y * iwx + v11.y * wx;
        acc.y += tp0 * iwy + bt * wy;
        tp0 = v00.z * iwx + v01.z * wx;
        bt  = v10.z * iwx + v11.z * wx;
        acc.z += tp0 * iwy + bt * wy;
        tp0 = v00.w * iwx + v01.w * wx;
        bt  = v10.w * iwx + v11.w * wx;
        acc.w += tp0 * iwy + bt * wy;

        tp_f4 av = { acc.x, acc.y, acc.z, acc.w };
        __builtin_nontemporal_store(av,
            (tp_f4*)(outrow + s * (TP_PLANES * TP_C)));
    }
}

extern "C" void kernel_launch(void* const* d_in, const int* in_sizes, int n_in,
                              void* d_out, int out_size, void* d_ws, size_t ws_size,
                              hipStream_t stream) {
    const float* pts = (const float*)d_in[0];
    const float* g[TP_SCALES] = {
        (const float*)d_in[1], (const float*)d_in[2],
        (const float*)d_in[3], (const float*)d_in[4] };
    float* out = (float*)d_out;

    const int res[TP_SCALES] = { 64, 128, 256, 512 };
    int N = in_sizes[0] / 3;

    // ws layout: [hist | binoff | keys | perm | transposed grids (16B aligned)]
    unsigned* hist   = (unsigned*)d_ws;
    unsigned* binoff = hist + TP_NBINS;
    unsigned* keys   = binoff + TP_NBINS;
    unsigned* perm   = keys + N;
    size_t meta = (size_t)2 * TP_NBINS + (size_t)2 * N;
    meta = (meta + 3) & ~(size_t)3;  // 16-byte align for float4 traffic
    float* tg[TP_SCALES];
    size_t off = meta;
    for (int s = 0; s < TP_SCALES; ++s) {
        tg[s] = (float*)d_ws + off;
        off += (size_t)TP_PLANES * TP_C * res[s] * res[s];
    }

    (void)hipMemsetAsync(hist, 0, TP_NBINS * sizeof(unsigned), stream);

    int pblocks = (N + 255) / 256;
    keys_kernel<<<pblocks, 256, 0, stream>>>(pts, keys, hist, N);

    transpose_all_kernel<<<TP_TILES3, 256, 0, stream>>>(
        g[0], g[1], g[2], g[3], tg[0], tg[1], tg[2], tg[3]);

    prefix_kernel<<<1, 1024, 0, stream>>>(hist, binoff);
    scatter_kernel<<<pblocks, 256, 0, stream>>>(keys, binoff, perm, N);

    int total = N * TP_PLANES * TP_CVEC;
    int block = 256;
    int grid = (total + block - 1) / block;
    triplane_gather_kernel<<<grid, block, 0, stream>>>(
        pts, perm, tg[0], tg[1], tg[2], tg[3], out, N);
}

// Round 4
// 690.963 us; speedup vs baseline: 1.1895x; 1.0511x over previous
//
#include <hip/hip_runtime.h>

// TriPlaneField: 4-scale triplane bilinear sampling with cumulative-sum concat.
// Pipeline:
//   (1) transpose_all_kernel: [3,C,r,r] fp32 -> [3,r,r,C] fp16 for all 4
//       scales in one launch. fp16 halves transpose-write + gather-read bytes
//       AND makes the whole transposed grid set (150 MB) L3-resident.
//   (2) Morton sort of points (5 bits/dim): keys+hist -> prefix -> scatter.
//       Spatial locality => big-scale texel reads hit L2/L3.
//   (3) gather: one thread per (point, plane, 8-channel group); half8 texel
//       loads, fp32 lerp math, non-temporal output stores (the 345 MB output
//       stream must not evict grid texels from L2/L3).

#define TP_C 72
#define TP_PLANES 3
#define TP_SCALES 4
#define TP_INV_BOUNDS 0.625f  // 1/1.6
#define TP_CVEC8 (TP_C / 8)   // 9 half8 groups per (n,p)

typedef float    tp_f4 __attribute__((ext_vector_type(4)));
typedef _Float16 tp_h4 __attribute__((ext_vector_type(4)));
typedef _Float16 tp_h8 __attribute__((ext_vector_type(8)));

// Transpose tile counts per scale: 3*r*r/128 -> 96, 384, 1536, 6144 (cumulative)
#define TP_TILES0 96
#define TP_TILES1 480
#define TP_TILES2 2016
#define TP_TILES3 8160

#define TP_NBINS 32768  // 5 bits per dim, 3D Morton

// ------------- fused transpose: [3,C,r,r] fp32 -> [3,r,r,C] fp16 -------------
__global__ __launch_bounds__(256) void transpose_all_kernel(
    const float* __restrict__ g0, const float* __restrict__ g1,
    const float* __restrict__ g2, const float* __restrict__ g3,
    _Float16* __restrict__ t0, _Float16* __restrict__ t1,
    _Float16* __restrict__ t2, _Float16* __restrict__ t3)
{
    int b = blockIdx.x;
    const float* in;
    _Float16* out;
    int rr, tile;
    if (b < TP_TILES0)      { in = g0; out = t0; rr = 64 * 64;   tile = b; }
    else if (b < TP_TILES1) { in = g1; out = t1; rr = 128 * 128; tile = b - TP_TILES0; }
    else if (b < TP_TILES2) { in = g2; out = t2; rr = 256 * 256; tile = b - TP_TILES1; }
    else                    { in = g3; out = t3; rr = 512 * 512; tile = b - TP_TILES2; }

    int P0  = tile * 128;       // global pixel index within [0, 3*rr)
    int p   = P0 / rr;          // plane
    int px0 = P0 - p * rr;      // pixel within plane

    // LDS tile: [72 channels][128 pixels], row stride 129 floats (pad 1)
    __shared__ float lds[TP_C * 129];

    const float* inp = in + ((size_t)p * TP_C) * (size_t)rr + px0;
    int t = threadIdx.x;

    // Load: 72 rows x 32 float4, coalesced within each 512B channel row.
    // Non-temporal: input is single-use, keep caches for the transposed copy.
    #pragma unroll
    for (int j = 0; j < 9; ++j) {
        int idx = j * 256 + t;
        int c   = idx >> 5;           // channel row (0..71)
        int q4  = idx & 31;           // float4 index within row (0..31)
        tp_f4 v = __builtin_nontemporal_load(
            (const tp_f4*)(inp + (size_t)c * rr + q4 * 4));
        float* l = lds + c * 129 + q4 * 4;
        l[0] = v.x; l[1] = v.y; l[2] = v.z; l[3] = v.w;
    }
    __syncthreads();

    // Store fp16: tile output = 128 px * 72 ch * 2B = 18432B contiguous.
    // idx in [0,2304): q = idx/18 (pixel), c4 = idx%18 (half4 channel group);
    // half offset = idx*4 (contiguous across idx) -> fully coalesced.
    _Float16* outp = out + (size_t)P0 * TP_C;
    #pragma unroll
    for (int j = 0; j < 9; ++j) {
        int idx = j * 256 + t;
        int q   = idx / 18;
        int c4  = idx - q * 18;
        const float* l = lds + (c4 * 4) * 129 + q;
        tp_h4 hv;
        hv.x = (_Float16)l[0 * 129];
        hv.y = (_Float16)l[1 * 129];
        hv.z = (_Float16)l[2 * 129];
        hv.w = (_Float16)l[3 * 129];
        *(tp_h4*)(outp + (size_t)idx * 4) = hv;
    }
}

// ---------------- Morton sort ----------------
__device__ __forceinline__ unsigned tp_expand5(unsigned v) {
    unsigned r = (v & 1);
    r |= (v & 2)  << 2;
    r |= (v & 4)  << 4;
    r |= (v & 8)  << 6;
    r |= (v & 16) << 8;
    return r;
}

__global__ __launch_bounds__(256) void keys_kernel(
    const float* __restrict__ pts, unsigned* __restrict__ keys,
    unsigned* __restrict__ hist, int N)
{
    int n = blockIdx.x * 256 + threadIdx.x;
    if (n >= N) return;
    float nx = fminf(fmaxf(-pts[n * 3 + 0] * TP_INV_BOUNDS, -1.f), 1.f);
    float ny = fminf(fmaxf(-pts[n * 3 + 1] * TP_INV_BOUNDS, -1.f), 1.f);
    float nz = fminf(fmaxf(-pts[n * 3 + 2] * TP_INV_BOUNDS, -1.f), 1.f);
    int qx = min(31, max(0, (int)((nx + 1.f) * 16.f)));
    int qy = min(31, max(0, (int)((ny + 1.f) * 16.f)));
    int qz = min(31, max(0, (int)((nz + 1.f) * 16.f)));
    unsigned key = tp_expand5((unsigned)qx)
                 | (tp_expand5((unsigned)qy) << 1)
                 | (tp_expand5((unsigned)qz) << 2);
    keys[n] = key;
    atomicAdd(&hist[key], 1u);
}

__global__ __launch_bounds__(1024) void prefix_kernel(
    const unsigned* __restrict__ hist, unsigned* __restrict__ binoff)
{
    __shared__ unsigned part[1024];
    int t = threadIdx.x;
    unsigned local[32];
    unsigned s = 0;
    #pragma unroll
    for (int i = 0; i < 32; ++i) { local[i] = hist[t * 32 + i]; s += local[i]; }
    part[t] = s;
    __syncthreads();
    for (int off = 1; off < 1024; off <<= 1) {
        unsigned v = (t >= off) ? part[t - off] : 0u;
        __syncthreads();
        part[t] += v;
        __syncthreads();
    }
    unsigned run = (t == 0) ? 0u : part[t - 1];
    #pragma unroll
    for (int i = 0; i < 32; ++i) { binoff[t * 32 + i] = run; run += local[i]; }
}

__global__ __launch_bounds__(256) void scatter_kernel(
    const unsigned* __restrict__ keys, unsigned* __restrict__ binoff,
    unsigned* __restrict__ perm, int N)
{
    int n = blockIdx.x * 256 + threadIdx.x;
    if (n >= N) return;
    unsigned pos = atomicAdd(&binoff[keys[n]], 1u);
    perm[pos] = n;
}

// ------------- gather: bilinear sample from fp16 channel-last grids -------------
__global__ __launch_bounds__(256) void triplane_gather_kernel(
    const float* __restrict__ pts,
    const unsigned* __restrict__ perm,
    const _Float16* __restrict__ t0,
    const _Float16* __restrict__ t1,
    const _Float16* __restrict__ t2,
    const _Float16* __restrict__ t3,
    float* __restrict__ out,
    int N)
{
    int idx = blockIdx.x * blockDim.x + threadIdx.x;
    int total = N * TP_PLANES * TP_CVEC8;
    if (idx >= total) return;

    int cv = idx % TP_CVEC8;          // which half8 group of channels (0..8)
    int t  = idx / TP_CVEC8;
    int p  = t % TP_PLANES;
    int ns = t / TP_PLANES;           // sorted point index
    int n  = (int)perm[ns];           // original point index

    float nx = -pts[n * 3 + 0] * TP_INV_BOUNDS;
    float ny = -pts[n * 3 + 1] * TP_INV_BOUNDS;
    float nz = -pts[n * 3 + 2] * TP_INV_BOUNDS;

    float cx, cy;
    if (p == 0)      { cx = nx; cy = ny; }
    else if (p == 1) { cx = nx; cy = nz; }
    else             { cx = ny; cy = nz; }

    const _Float16* grids[TP_SCALES] = { t0, t1, t2, t3 };
    const int       res[TP_SCALES]   = { 64, 128, 256, 512 };

    float acc[8];
    #pragma unroll
    for (int k = 0; k < 8; ++k) acc[k] = 0.f;

    float* outrow = out + (size_t)n * (TP_SCALES * TP_PLANES * TP_C)
                        + (size_t)p * TP_C + cv * 8;

    #pragma unroll
    for (int s = 0; s < TP_SCALES; ++s) {
        const int r = res[s];
        const float rm1 = (float)(r - 1);

        float fx = (cx + 1.0f) * 0.5f * rm1;
        float fy = (cy + 1.0f) * 0.5f * rm1;
        fx = fminf(fmaxf(fx, 0.0f), rm1);
        fy = fminf(fmaxf(fy, 0.0f), rm1);

        float x0f = floorf(fx);
        float y0f = floorf(fy);
        float wx = fx - x0f;
        float wy = fy - y0f;
        int x0 = (int)x0f;
        int y0 = (int)y0f;
        int x1 = min(x0 + 1, r - 1);
        int y1 = min(y0 + 1, r - 1);

        // channel-last: ((p*r + y)*r + x)*C + c, fp16
        const _Float16* g = grids[s] + ((size_t)p * r * r) * TP_C + (size_t)cv * 8;
        tp_h8 v00 = *(const tp_h8*)(g + ((size_t)y0 * r + x0) * TP_C);
        tp_h8 v01 = *(const tp_h8*)(g + ((size_t)y0 * r + x1) * TP_C);
        tp_h8 v10 = *(const tp_h8*)(g + ((size_t)y1 * r + x0) * TP_C);
        tp_h8 v11 = *(const tp_h8*)(g + ((size_t)y1 * r + x1) * TP_C);

        float iwx = 1.0f - wx;
        float iwy = 1.0f - wy;

        #pragma unroll
        for (int k = 0; k < 8; ++k) {
            float a00 = (float)v00[k];
            float a01 = (float)v01[k];
            float a10 = (float)v10[k];
            float a11 = (float)v11[k];
            float top = a00 * iwx + a01 * wx;
            float bot = a10 * iwx + a11 * wx;
            acc[k] += top * iwy + bot * wy;
        }

        tp_f4 lo = { acc[0], acc[1], acc[2], acc[3] };
        tp_f4 hi = { acc[4], acc[5], acc[6], acc[7] };
        float* orow = outrow + s * (TP_PLANES * TP_C);
        __builtin_nontemporal_store(lo, (tp_f4*)orow);
        __builtin_nontemporal_store(hi, (tp_f4*)(orow + 4));
    }
}

extern "C" void kernel_launch(void* const* d_in, const int* in_sizes, int n_in,
                              void* d_out, int out_size, void* d_ws, size_t ws_size,
                              hipStream_t stream) {
    const float* pts = (const float*)d_in[0];
    const float* g[TP_SCALES] = {
        (const float*)d_in[1], (const float*)d_in[2],
        (const float*)d_in[3], (const float*)d_in[4] };
    float* out = (float*)d_out;

    const int res[TP_SCALES] = { 64, 128, 256, 512 };
    int N = in_sizes[0] / 3;

    // ws layout: [hist | binoff | keys | perm | fp16 transposed grids (16B aligned)]
    unsigned* hist   = (unsigned*)d_ws;
    unsigned* binoff = hist + TP_NBINS;
    unsigned* keys   = binoff + TP_NBINS;
    unsigned* perm   = keys + N;
    size_t meta = (size_t)2 * TP_NBINS + (size_t)2 * N;
    meta = (meta + 3) & ~(size_t)3;  // 16-byte align

    _Float16* tg[TP_SCALES];
    _Float16* tgbase = (_Float16*)((float*)d_ws + meta);
    size_t off = 0;
    for (int s = 0; s < TP_SCALES; ++s) {
        tg[s] = tgbase + off;
        off += (size_t)TP_PLANES * TP_C * res[s] * res[s];
    }

    (void)hipMemsetAsync(hist, 0, TP_NBINS * sizeof(unsigned), stream);

    int pblocks = (N + 255) / 256;
    keys_kernel<<<pblocks, 256, 0, stream>>>(pts, keys, hist, N);

    transpose_all_kernel<<<TP_TILES3, 256, 0, stream>>>(
        g[0], g[1], g[2], g[3], tg[0], tg[1], tg[2], tg[3]);

    prefix_kernel<<<1, 1024, 0, stream>>>(hist, binoff);
    scatter_kernel<<<pblocks, 256, 0, stream>>>(keys, binoff, perm, N);

    int total = N * TP_PLANES * TP_CVEC8;
    int block = 256;
    int grid = (total + block - 1) / block;
    triplane_gather_kernel<<<grid, block, 0, stream>>>(
        pts, perm, tg[0], tg[1], tg[2], tg[3], out, N);
}